// Round 2
// baseline (1180.848 us; speedup 1.0000x reference)
//
#include <hip/hip_runtime.h>
#include <math.h>

#define SLOPE 0.01f

__device__ __forceinline__ float lrelu(float v) { return v >= 0.f ? v : SLOPE * v; }

// ---------------------------------------------------------------------------
// GRU step (h0=0) for both layers, regenerate GCN weights, fold Wout/bout.
// ---------------------------------------------------------------------------
__global__ void prep_k(const float* __restrict__ m1, const float* __restrict__ Wih1,
                       const float* __restrict__ bih1, const float* __restrict__ bhh1,
                       const float* __restrict__ m2, const float* __restrict__ Wih2,
                       const float* __restrict__ bih2, const float* __restrict__ bhh2,
                       const float* __restrict__ wtW1, const float* __restrict__ wtb1,
                       const float* __restrict__ wtW2, const float* __restrict__ wtb2,
                       const float* __restrict__ Wout, const float* __restrict__ bout,
                       float* __restrict__ Wn1, float* __restrict__ Wn2,
                       float* __restrict__ wsum, float* __restrict__ bsum) {
    __shared__ float nm[32];   // new_mem1 [0..15], new_mem2 [16..31]
    int t = threadIdx.x;
    if (t < 32) {
        int L = t >> 4, j = t & 15;
        const float* m   = L ? m2   : m1;
        const float* Wih = L ? Wih2 : Wih1;
        const float* bih = L ? bih2 : bih1;
        const float* bhh = L ? bhh2 : bhh1;
        float gr = bih[j], gz = bih[16 + j], gn = bih[32 + j];
        for (int k = 0; k < 16; ++k) {
            float mk = m[k];
            gr += Wih[j * 16 + k] * mk;
            gz += Wih[(16 + j) * 16 + k] * mk;
            gn += Wih[(32 + j) * 16 + k] * mk;
        }
        float r = 1.f / (1.f + expf(-(gr + bhh[j])));
        float z = 1.f / (1.f + expf(-(gz + bhh[16 + j])));
        float n = tanhf(gn + r * bhh[32 + j]);
        nm[t] = (1.f - z) * n;          // + z*h, h==0
    }
    __syncthreads();
    float s1 = wtb1[t], s2 = wtb2[t];
    for (int k = 0; k < 16; ++k) {
        s1 += wtW1[t * 16 + k] * nm[k];
        s2 += wtW2[t * 16 + k] * nm[16 + k];
    }
    Wn1[t] = s1;
    Wn2[t] = s2;
    if (t < 16) wsum[t] = Wout[t] + Wout[16 + t];
    if (t == 0) bsum[0] = bout[0] + bout[1];
}

// ---------------------------------------------------------------------------
// CSR build: zero counts -> histogram -> scan(off,cur,dis) -> fill(srcs,nrm)
// ---------------------------------------------------------------------------
__global__ void zero_k(int* __restrict__ cnt, int N) {
    int i = blockIdx.x * 256 + threadIdx.x;
    if (i < N) cnt[i] = 0;
}

__global__ void hist_k(int* __restrict__ cnt, const int* __restrict__ col, int E) {
    int e = blockIdx.x * 256 + threadIdx.x;
    if (e < E) atomicAdd(cnt + col[e], 1);
}

__global__ __launch_bounds__(1024) void scan_k(const int* __restrict__ cnt,
                                               int* __restrict__ off, int* __restrict__ cur,
                                               float* __restrict__ dis, int N) {
    __shared__ int sums[1024];
    int t = threadIdx.x;
    int chunk = (N + 1023) >> 10;
    int lo = t * chunk, hi = min(lo + chunk, N);
    int s = 0;
    for (int i = lo; i < hi; ++i) s += cnt[i];
    sums[t] = s;
    __syncthreads();
    for (int d = 1; d < 1024; d <<= 1) {
        int v = sums[t];
        int u = (t >= d) ? sums[t - d] : 0;
        __syncthreads();
        sums[t] = v + u;
        __syncthreads();
    }
    int run = (t == 0) ? 0 : sums[t - 1];
    for (int i = lo; i < hi; ++i) {
        off[i] = run;
        cur[i] = run;
        int c = cnt[i];
        dis[i] = rsqrtf((float)(c + 1));   // in-degree + self-loop
        run += c;
    }
    if (t == 0) off[N] = sums[1023];
}

__global__ void fill_k(const int* __restrict__ row, const int* __restrict__ col,
                       const float* __restrict__ dis, int* __restrict__ cur,
                       int* __restrict__ srcs, float* __restrict__ nrm, int E) {
    int e = blockIdx.x * 256 + threadIdx.x;
    if (e >= E) return;
    int r = row[e], d = col[e];
    int pos = atomicAdd(cur + d, 1);
    srcs[pos] = r;
    nrm[pos] = dis[r] * dis[d];
}

// ---------------------------------------------------------------------------
// Fused MLP: xl1 = leaky(leaky(x@W1^T+b1)@W2^T+b2) @ Wn1^T
// 64 nodes/block in LDS (transposed), 4 waves own 64-hu quarters each,
// wave-uniform W1/W2 offsets (readfirstlane) -> s_load broadcast.
// ---------------------------------------------------------------------------
__global__ __launch_bounds__(256, 3) void mlp_k(
        const float* __restrict__ x, const float* __restrict__ W1,
        const float* __restrict__ b1, const float* __restrict__ W2,
        const float* __restrict__ b2, const float* __restrict__ Wn1,
        float* __restrict__ xl, int N) {
    __shared__ float xs[128 * 64];       // xs[k*64+n]; reused as h2s[n*17+j]
    __shared__ float part[4 * 64 * 17];  // part[(q*64+n)*17+j]
    const int t    = threadIdx.x;
    const int nl   = t & 63;
    const int q    = __builtin_amdgcn_readfirstlane(t >> 6);  // wave-uniform
    const int node = blockIdx.x * 64 + nl;

    // ---- stage x tile (transposed, conflict-free) ----
    if (node < N) {
        const float4* xr = (const float4*)(x + (size_t)node * 128) + q * 8;
#pragma unroll
        for (int kk = 0; kk < 8; ++kk) {
            float4 v = xr[kk];
            int k = q * 32 + kk * 4;
            xs[(k + 0) * 64 + nl] = v.x;
            xs[(k + 1) * 64 + nl] = v.y;
            xs[(k + 2) * 64 + nl] = v.z;
            xs[(k + 3) * 64 + nl] = v.w;
        }
    } else {
#pragma unroll
        for (int kk = 0; kk < 32; ++kk) xs[(q * 32 + kk) * 64 + nl] = 0.f;
    }
    __syncthreads();

    // ---- stage 1+2: this wave's 64 hu values, 8 at a time ----
    float acc2[16];
#pragma unroll
    for (int j = 0; j < 16; ++j) acc2[j] = 0.f;
    for (int hh = 0; hh < 64; hh += 8) {
        const int hu0 = q * 64 + hh;
        const float* wb = W1 + (size_t)hu0 * 128;
        float a[8];
#pragma unroll
        for (int r = 0; r < 8; ++r) a[r] = 0.f;
        for (int k = 0; k < 128; ++k) {
            float xv = xs[k * 64 + nl];
#pragma unroll
            for (int r = 0; r < 8; ++r) a[r] = fmaf(wb[r * 128 + k], xv, a[r]);
        }
#pragma unroll
        for (int r = 0; r < 8; ++r) {
            float h1 = lrelu(a[r] + b1[hu0 + r]);
#pragma unroll
            for (int j = 0; j < 16; ++j)
                acc2[j] = fmaf(W2[j * 256 + hu0 + r], h1, acc2[j]);
        }
    }
#pragma unroll
    for (int j = 0; j < 16; ++j) part[(q * 64 + nl) * 17 + j] = acc2[j];
    __syncthreads();

    // ---- h2 = lrelu(sum over quarters + b2) -> reuse xs as h2s[n*17+j] ----
    {
        const int j0 = q * 4;
#pragma unroll
        for (int jj = 0; jj < 4; ++jj) {
            int j = j0 + jj;
            float s = b2[j];
#pragma unroll
            for (int qq = 0; qq < 4; ++qq) s += part[(qq * 64 + nl) * 17 + j];
            xs[nl * 17 + j] = lrelu(s);
        }
    }
    __syncthreads();

    // ---- stage 3: o = h2 @ Wn1^T (this wave: channels q*4..q*4+3) ----
    {
        const int c0 = q * 4;
        float o[4];
#pragma unroll
        for (int cc = 0; cc < 4; ++cc) {
            float s = 0.f;
#pragma unroll
            for (int j = 0; j < 16; ++j)
                s = fmaf(Wn1[(c0 + cc) * 16 + j], xs[nl * 17 + j], s);
            o[cc] = s;
        }
        if (node < N) {
            float4* xo = (float4*)(xl + (size_t)node * 16 + c0);
            *xo = make_float4(o[0], o[1], o[2], o[3]);
        }
    }
}

// ---------------------------------------------------------------------------
// Gather layer 1: agg = bias + self + sum_in(nrm * xl1[src]); then
// xl2 = leaky(agg) @ Wn2^T  (16 lanes per node, shfl width 16)
// ---------------------------------------------------------------------------
__global__ void gather1_k(const int* __restrict__ off, const int* __restrict__ srcs,
                          const float* __restrict__ nrm, const float* __restrict__ dis,
                          const float* __restrict__ xin, const float* __restrict__ bias,
                          const float* __restrict__ Wn2, float* __restrict__ xout, int N) {
    __shared__ float w[256];             // transposed: w[j*16+c] = Wn2[c*16+j]
    {
        int j = threadIdx.x >> 4, c = threadIdx.x & 15;
        w[threadIdx.x] = Wn2[c * 16 + j];
    }
    __syncthreads();
    int t = blockIdx.x * 256 + threadIdx.x;
    int n = t >> 4, c = t & 15;
    if (n >= N) return;
    float d = dis[n];
    float acc = bias[c] + d * d * xin[(size_t)n * 16 + c];
    int e0 = off[n], e1 = off[n + 1];
    for (int e = e0; e < e1; ++e) {
        int s = srcs[e];
        acc = fmaf(nrm[e], xin[(size_t)s * 16 + c], acc);
    }
    float h = lrelu(acc);
    float o = 0.f;
#pragma unroll
    for (int j = 0; j < 16; ++j) o = fmaf(w[j * 16 + c], __shfl(h, j, 16), o);
    xout[(size_t)n * 16 + c] = o;
}

// ---------------------------------------------------------------------------
// Gather layer 2 + final projection: out[n] = bsum + sum_c wsum[c]*leaky(agg[c])
// ---------------------------------------------------------------------------
__global__ void gather2_k(const int* __restrict__ off, const int* __restrict__ srcs,
                          const float* __restrict__ nrm, const float* __restrict__ dis,
                          const float* __restrict__ xin, const float* __restrict__ bias,
                          const float* __restrict__ wsum, const float* __restrict__ bsum,
                          float* __restrict__ out, int N) {
    int t = blockIdx.x * 256 + threadIdx.x;
    int n = t >> 4, c = t & 15;
    if (n >= N) return;
    float d = dis[n];
    float acc = bias[c] + d * d * xin[(size_t)n * 16 + c];
    int e0 = off[n], e1 = off[n + 1];
    for (int e = e0; e < e1; ++e)
        acc = fmaf(nrm[e], xin[(size_t)srcs[e] * 16 + c], acc);
    float v = wsum[c] * lrelu(acc);
#pragma unroll
    for (int m = 8; m >= 1; m >>= 1) v += __shfl_xor(v, m, 16);
    if (c == 0) out[n] = v + bsum[0];
}

// ---------------------------------------------------------------------------
extern "C" void kernel_launch(void* const* d_in, const int* in_sizes, int n_in,
                              void* d_out, int out_size, void* d_ws, size_t ws_size,
                              hipStream_t stream) {
    const float* x      = (const float*)d_in[0];
    const int*   edge   = (const int*)d_in[1];
    const float* W1     = (const float*)d_in[2];
    const float* b1     = (const float*)d_in[3];
    const float* W2     = (const float*)d_in[4];
    const float* b2     = (const float*)d_in[5];
    const float* mem1   = (const float*)d_in[6];
    const float* g1_Wih = (const float*)d_in[7];
    const float* g1_bih = (const float*)d_in[9];
    const float* g1_bhh = (const float*)d_in[10];
    const float* wt1_W  = (const float*)d_in[11];
    const float* wt1_b  = (const float*)d_in[12];
    const float* gcn1_b = (const float*)d_in[13];
    const float* mem2   = (const float*)d_in[14];
    const float* g2_Wih = (const float*)d_in[15];
    const float* g2_bih = (const float*)d_in[17];
    const float* g2_bhh = (const float*)d_in[18];
    const float* wt2_W  = (const float*)d_in[19];
    const float* wt2_b  = (const float*)d_in[20];
    const float* gcn2_b = (const float*)d_in[21];
    const float* Wout   = (const float*)d_in[22];
    const float* bout   = (const float*)d_in[23];
    float* out = (float*)d_out;

    const int N = in_sizes[0] / 128;
    const int E = in_sizes[1] / 2;
    const int* row = edge;
    const int* col = edge + E;

    float* ws   = (float*)d_ws;
    float* bufA = ws;                         // [N*16] xl1
    float* bufB = bufA + (size_t)N * 16;      // [N*16] xl2
    float* dis  = bufB + (size_t)N * 16;      // [N]
    float* nrm  = dis + N;                    // [E]
    float* sm   = nrm + E;                    // smalls (544 floats)
    float* Wn1  = sm;
    float* Wn2  = sm + 256;
    float* wsum = sm + 512;
    float* bsum = sm + 528;
    int*   cnt  = (int*)(sm + 544);           // [N]
    int*   off  = cnt + N;                    // [N+1]
    int*   cur  = off + N + 1;                // [N]
    int*   srcs = cur + N;                    // [E]

    const int gN  = (N + 255) / 256;
    const int gE  = (E + 255) / 256;
    const int gM  = (N + 63) / 64;
    const int gG  = (N * 16 + 255) / 256;

    prep_k<<<1, 256, 0, stream>>>(mem1, g1_Wih, g1_bih, g1_bhh,
                                  mem2, g2_Wih, g2_bih, g2_bhh,
                                  wt1_W, wt1_b, wt2_W, wt2_b,
                                  Wout, bout, Wn1, Wn2, wsum, bsum);
    zero_k<<<gN, 256, 0, stream>>>(cnt, N);
    hist_k<<<gE, 256, 0, stream>>>(cnt, col, E);
    scan_k<<<1, 1024, 0, stream>>>(cnt, off, cur, dis, N);
    fill_k<<<gE, 256, 0, stream>>>(row, col, dis, cur, srcs, nrm, E);
    mlp_k<<<gM, 256, 0, stream>>>(x, W1, b1, W2, b2, Wn1, bufA, N);
    gather1_k<<<gG, 256, 0, stream>>>(off, srcs, nrm, dis, bufA, gcn1_b, Wn2, bufB, N);
    gather2_k<<<gG, 256, 0, stream>>>(off, srcs, nrm, dis, bufB, gcn2_b, wsum, bsum, out, N);
}